// Round 2
// baseline (3521.027 us; speedup 1.0000x reference)
//
#include <hip/hip_runtime.h>
#include <hip/hip_bf16.h>

#define BB 128
#define TT 25
#define VOCAB 10000
#define HIDD 512

__device__ __forceinline__ float sigmoidf_(float x) { return 1.0f / (1.0f + __expf(-x)); }

// =====================================================================
// Recurrence-core tiled GEMM: BM=16, BN=64, BK=64, 256 threads.
// Thread (tx=tid&15, ty=tid>>4): 1 row (ty), 4 cols (tx*4..+3).
// Within a wave ty spans 0..3 -> A scalar reads are 4-addr broadcasts;
// B float4 reads are 256B contiguous across tx -> conflict-free.
// =====================================================================

// h0 = tanh(vgg @ W_in + b_in): M=128, K=4096, N=512. grid (8,8)
__global__ __launch_bounds__(256) void k_h0(const float* __restrict__ A,
                                            const float* __restrict__ W,
                                            const float* __restrict__ bias,
                                            float* __restrict__ o1,
                                            float* __restrict__ o2)
{
    __shared__ float As[16][68];
    __shared__ float Bs[64][68];
    const int tid = threadIdx.x;
    const int tx = tid & 15, ty = tid >> 4;
    const int n0 = blockIdx.x * 64, m0 = blockIdx.y * 16;
    float acc[4] = {0.f, 0.f, 0.f, 0.f};

    for (int k0 = 0; k0 < 4096; k0 += 64) {
        *(float4*)&As[ty][tx * 4] =
            *(const float4*)&A[(size_t)(m0 + ty) * 4096 + k0 + tx * 4];
        #pragma unroll
        for (int l = 0; l < 4; ++l) {
            int idx = tid + l * 256;
            int r = idx >> 4, c = (idx & 15) * 4;
            *(float4*)&Bs[r][c] = *(const float4*)&W[(size_t)(k0 + r) * 512 + n0 + c];
        }
        __syncthreads();
        #pragma unroll 8
        for (int kk = 0; kk < 64; ++kk) {
            float a = As[ty][kk];
            float4 b = *(float4*)&Bs[kk][tx * 4];
            acc[0] += a * b.x; acc[1] += a * b.y;
            acc[2] += a * b.z; acc[3] += a * b.w;
        }
        __syncthreads();
    }
    int m = m0 + ty, n = n0 + tx * 4;
    float4 r4;
    r4.x = tanhf(acc[0] + bias[n + 0]);
    r4.y = tanhf(acc[1] + bias[n + 1]);
    r4.z = tanhf(acc[2] + bias[n + 2]);
    r4.w = tanhf(acc[3] + bias[n + 3]);
    *(float4*)&o1[m * 512 + n] = r4;
    *(float4*)&o2[m * 512 + n] = r4;
}

// gates: gu|gr = sigmoid([x,h] @ W + b). M=128, K=1024, N=512.
// grid (8, 8, 2): z=0 -> (Wu,bu,gu), z=1 -> (Wr,br,gr).
// x source: xbuf (fp32 [128,512]) if non-null, else emb[toks[m*TT+t]].
__global__ __launch_bounds__(256) void k_gates(const float* __restrict__ h,
                                               const float* __restrict__ xbuf,
                                               const float* __restrict__ emb,
                                               const int* __restrict__ toks, int t,
                                               const float* __restrict__ Wu,
                                               const float* __restrict__ bu,
                                               float* __restrict__ gu,
                                               const float* __restrict__ Wr,
                                               const float* __restrict__ br,
                                               float* __restrict__ gr)
{
    __shared__ float As[16][68];
    __shared__ float Bs[64][68];
    const float* W    = blockIdx.z ? Wr : Wu;
    const float* bias = blockIdx.z ? br : bu;
    float*       out  = blockIdx.z ? gr : gu;
    const int tid = threadIdx.x;
    const int tx = tid & 15, ty = tid >> 4;
    const int n0 = blockIdx.x * 64, m0 = blockIdx.y * 16;
    float acc[4] = {0.f, 0.f, 0.f, 0.f};

    for (int k0 = 0; k0 < 1024; k0 += 64) {
        int m = m0 + ty;
        int k = k0 + tx * 4;
        float4 av;
        if (k0 < 512) {
            if (xbuf) av = *(const float4*)&xbuf[(size_t)m * 512 + k];
            else {
                int tok = toks[m * TT + t];
                av = *(const float4*)&emb[(size_t)tok * 512 + k];
            }
        } else {
            av = *(const float4*)&h[(size_t)m * 512 + (k - 512)];
        }
        *(float4*)&As[ty][tx * 4] = av;
        #pragma unroll
        for (int l = 0; l < 4; ++l) {
            int idx = tid + l * 256;
            int r = idx >> 4, c = (idx & 15) * 4;
            *(float4*)&Bs[r][c] = *(const float4*)&W[(size_t)(k0 + r) * 512 + n0 + c];
        }
        __syncthreads();
        #pragma unroll 8
        for (int kk = 0; kk < 64; ++kk) {
            float a = As[ty][kk];
            float4 b = *(float4*)&Bs[kk][tx * 4];
            acc[0] += a * b.x; acc[1] += a * b.y;
            acc[2] += a * b.z; acc[3] += a * b.w;
        }
        __syncthreads();
    }
    int m = m0 + ty, n = n0 + tx * 4;
    float4 r4;
    r4.x = sigmoidf_(acc[0] + bias[n + 0]);
    r4.y = sigmoidf_(acc[1] + bias[n + 1]);
    r4.z = sigmoidf_(acc[2] + bias[n + 2]);
    r4.w = sigmoidf_(acc[3] + bias[n + 3]);
    *(float4*)&out[m * 512 + n] = r4;
}

// cand: hh = tanh([x, gr*h] @ Wc + bc); hnew = gu*h + (1-gu)*hh
// writes hnew (ping-pong target), optionally s1all_t (s1all + t*128*512).
__global__ __launch_bounds__(256) void k_cand(const float* __restrict__ h,
                                              const float* __restrict__ xbuf,
                                              const float* __restrict__ emb,
                                              const int* __restrict__ toks, int t,
                                              const float* __restrict__ Wc,
                                              const float* __restrict__ bc,
                                              const float* __restrict__ gu,
                                              const float* __restrict__ gr,
                                              float* __restrict__ hnew,
                                              float* __restrict__ s1all_t)
{
    __shared__ float As[16][68];
    __shared__ float Bs[64][68];
    const int tid = threadIdx.x;
    const int tx = tid & 15, ty = tid >> 4;
    const int n0 = blockIdx.x * 64, m0 = blockIdx.y * 16;
    float acc[4] = {0.f, 0.f, 0.f, 0.f};

    for (int k0 = 0; k0 < 1024; k0 += 64) {
        int m = m0 + ty;
        int k = k0 + tx * 4;
        float4 av;
        if (k0 < 512) {
            if (xbuf) av = *(const float4*)&xbuf[(size_t)m * 512 + k];
            else {
                int tok = toks[m * TT + t];
                av = *(const float4*)&emb[(size_t)tok * 512 + k];
            }
        } else {
            size_t base = (size_t)m * 512 + (k - 512);
            float4 g  = *(const float4*)&gr[base];
            float4 hv = *(const float4*)&h[base];
            av.x = g.x * hv.x; av.y = g.y * hv.y;
            av.z = g.z * hv.z; av.w = g.w * hv.w;
        }
        *(float4*)&As[ty][tx * 4] = av;
        #pragma unroll
        for (int l = 0; l < 4; ++l) {
            int idx = tid + l * 256;
            int r = idx >> 4, c = (idx & 15) * 4;
            *(float4*)&Bs[r][c] = *(const float4*)&Wc[(size_t)(k0 + r) * 512 + n0 + c];
        }
        __syncthreads();
        #pragma unroll 8
        for (int kk = 0; kk < 64; ++kk) {
            float a = As[ty][kk];
            float4 b = *(float4*)&Bs[kk][tx * 4];
            acc[0] += a * b.x; acc[1] += a * b.y;
            acc[2] += a * b.z; acc[3] += a * b.w;
        }
        __syncthreads();
    }
    int m = m0 + ty, n = n0 + tx * 4;
    size_t base = (size_t)m * 512 + n;
    float4 g  = *(const float4*)&gu[base];
    float4 ho = *(const float4*)&h[base];
    float4 r4;
    r4.x = g.x * ho.x + (1.f - g.x) * tanhf(acc[0] + bc[n + 0]);
    r4.y = g.y * ho.y + (1.f - g.y) * tanhf(acc[1] + bc[n + 1]);
    r4.z = g.z * ho.z + (1.f - g.z) * tanhf(acc[2] + bc[n + 2]);
    r4.w = g.w * ho.w + (1.f - g.w) * tanhf(acc[3] + bc[n + 3]);
    *(float4*)&hnew[base] = r4;
    if (s1all_t) *(float4*)&s1all_t[base] = r4;
}

// logits: out[b,t,:] = s1all[t*128+b,:] @ Wout + bout
// M=3200, K=512, N=10000. BM=64, BN=64, BK=32; thread tile 4x4. grid (157,50)
__global__ __launch_bounds__(256) void k_logits(const float* __restrict__ A,
                                                const float* __restrict__ W,
                                                const float* __restrict__ bias,
                                                float* __restrict__ out)
{
    __shared__ float As[64][36];
    __shared__ float Bs[32][68];
    const int tid = threadIdx.x;
    const int tx = tid & 15, ty = tid >> 4;
    const int n0 = blockIdx.x * 64, m0 = blockIdx.y * 64;
    float acc[4][4];
    #pragma unroll
    for (int i = 0; i < 4; ++i)
        #pragma unroll
        for (int j = 0; j < 4; ++j) acc[i][j] = 0.f;

    for (int k0 = 0; k0 < 512; k0 += 32) {
        #pragma unroll
        for (int l = 0; l < 2; ++l) {
            int idx = tid + l * 256;
            int r = idx >> 3, c = (idx & 7) * 4;
            *(float4*)&As[r][c] = *(const float4*)&A[(size_t)(m0 + r) * 512 + k0 + c];
        }
        #pragma unroll
        for (int l = 0; l < 2; ++l) {
            int idx = tid + l * 256;
            int r = idx >> 4, c = (idx & 15) * 4;
            int gcol = n0 + c;
            float4 bv = {0.f, 0.f, 0.f, 0.f};
            if (gcol < VOCAB)
                bv = *(const float4*)&W[(size_t)(k0 + r) * VOCAB + gcol];
            *(float4*)&Bs[r][c] = bv;
        }
        __syncthreads();
        #pragma unroll 4
        for (int kk = 0; kk < 32; ++kk) {
            float4 b = *(float4*)&Bs[kk][tx * 4];
            float a0 = As[ty * 4 + 0][kk];
            float a1 = As[ty * 4 + 1][kk];
            float a2 = As[ty * 4 + 2][kk];
            float a3 = As[ty * 4 + 3][kk];
            acc[0][0] += a0 * b.x; acc[0][1] += a0 * b.y; acc[0][2] += a0 * b.z; acc[0][3] += a0 * b.w;
            acc[1][0] += a1 * b.x; acc[1][1] += a1 * b.y; acc[1][2] += a1 * b.z; acc[1][3] += a1 * b.w;
            acc[2][0] += a2 * b.x; acc[2][1] += a2 * b.y; acc[2][2] += a2 * b.z; acc[2][3] += a2 * b.w;
            acc[3][0] += a3 * b.x; acc[3][1] += a3 * b.y; acc[3][2] += a3 * b.z; acc[3][3] += a3 * b.w;
        }
        __syncthreads();
    }

    int n = n0 + tx * 4;
    if (n < VOCAB) {
        float b0 = bias[n + 0], b1 = bias[n + 1], b2 = bias[n + 2], b3 = bias[n + 3];
        #pragma unroll
        for (int i = 0; i < 4; ++i) {
            int m = m0 + ty * 4 + i;
            int tt = m >> 7;        // m / 128
            int bb = m & 127;       // m % 128
            float4 r4;
            r4.x = acc[i][0] + b0; r4.y = acc[i][1] + b1;
            r4.z = acc[i][2] + b2; r4.w = acc[i][3] + b3;
            *(float4*)&out[(size_t)bb * TT * VOCAB + (size_t)tt * VOCAB + n] = r4;
        }
    }
}

__global__ void k_states(const float* __restrict__ s0, const float* __restrict__ s1,
                         float* __restrict__ out)
{
    int i = blockIdx.x * 256 + threadIdx.x;
    if (i < BB * HIDD) {
        out[i] = s0[i];
        out[BB * HIDD + i] = s1[i];
    }
}

extern "C" void kernel_launch(void* const* d_in, const int* in_sizes, int n_in,
                              void* d_out, int out_size, void* d_ws, size_t ws_size,
                              hipStream_t stream)
{
    const float* vgg  = (const float*)d_in[0];
    const int*   toks = (const int*)d_in[1];
    const float* emb  = (const float*)d_in[3];
    const float* Win  = (const float*)d_in[4];
    const float* bin  = (const float*)d_in[5];
    const float* Wu0  = (const float*)d_in[6];
    const float* bu0  = (const float*)d_in[7];
    const float* Wr0  = (const float*)d_in[8];
    const float* br0  = (const float*)d_in[9];
    const float* Wc0  = (const float*)d_in[10];
    const float* bc0  = (const float*)d_in[11];
    const float* Wu1  = (const float*)d_in[12];
    const float* bu1  = (const float*)d_in[13];
    const float* Wr1  = (const float*)d_in[14];
    const float* br1  = (const float*)d_in[15];
    const float* Wc1  = (const float*)d_in[16];
    const float* bc1  = (const float*)d_in[17];
    const float* Wout = (const float*)d_in[18];
    const float* bout = (const float*)d_in[19];

    float* ws = (float*)d_ws;
    float* s0a = ws;                    // 128*512
    float* s0b = s0a + BB * HIDD;
    float* s1a = s0b + BB * HIDD;
    float* s1b = s1a + BB * HIDD;
    float* gu  = s1b + BB * HIDD;
    float* gr  = gu + BB * HIDD;
    float* s1all = gr + BB * HIDD;      // 3200*512

    float* out = (float*)d_out;

    k_h0<<<dim3(8, 8), 256, 0, stream>>>(vgg, Win, bin, s0a, s1a);

    for (int t = 0; t < TT; ++t) {
        // layer 0: x = emb[toks[:,t]], h = s0a -> s0b
        k_gates<<<dim3(8, 8, 2), 256, 0, stream>>>(s0a, nullptr, emb, toks, t,
                                                   Wu0, bu0, gu, Wr0, br0, gr);
        k_cand<<<dim3(8, 8), 256, 0, stream>>>(s0a, nullptr, emb, toks, t,
                                               Wc0, bc0, gu, gr, s0b, nullptr);
        // layer 1: x = s0b (new), h = s1a -> s1b (+ s1all row t)
        k_gates<<<dim3(8, 8, 2), 256, 0, stream>>>(s1a, s0b, emb, toks, t,
                                                   Wu1, bu1, gu, Wr1, br1, gr);
        k_cand<<<dim3(8, 8), 256, 0, stream>>>(s1a, s0b, emb, toks, t,
                                               Wc1, bc1, gu, gr, s1b,
                                               s1all + (size_t)t * BB * HIDD);
        float* tmp;
        tmp = s0a; s0a = s0b; s0b = tmp;
        tmp = s1a; s1a = s1b; s1b = tmp;
    }

    k_logits<<<dim3(157, 50), 256, 0, stream>>>(s1all, Wout, bout, out);

    k_states<<<dim3((BB * HIDD + 255) / 256), 256, 0, stream>>>(
        s0a, s1a, out + (size_t)TT * BB * VOCAB);
}